// Round 6
// baseline (232.852 us; speedup 1.0000x reference)
//
#include <hip/hip_runtime.h>

// SpikeFP32LayerNorm: LayerNorm (no affine) over rows of (8192, 4096) fp32,
// statistics + normalization in FP64 per the reference circuit:
//   mean = sum(x64)/N ; c = x64 - mean ; var = sum(c*c)/N ; vpe = var + 1e-6
//   y = 1/vpe ; 5x NR: y = 0.5*y*(3 - vpe*y*y) ; out = fp32(c * y)
//
// v7: global_load_lds DMA staging (last untested load path).
//   2x2 complete: flat-NT loads plateau at ~58us (4.6 TB/s) across 4
//   schedules; flat-cached loads 79.8us (L2-install wall). Store policy
//   irrelevant. The one remaining high-throughput read mechanism on gfx950
//   is the async global->LDS DMA (known-good: GEMM ladder stages at
//   multi-TB/s through it, m97/m103).
//   Structure: 2x16KB LDS double-buffer; each wave DMAs and consumes its
//   OWN quarter-row (no cross-wave staging dependency); reduce barriers are
//   raw s_barrier + lgkmcnt(0) (NOT __syncthreads -- its vmcnt(0) would
//   drain the in-flight next-row DMAs = m97 barrier-drain trap); counted
//   vmcnt(8) keeps next-row DMA + prev-row stores in flight.
//   LDS 32KB/block -> 4 blocks/CU -> grid 1024 x 8 rows.
// Per-lane element mapping identical to v3 -> bit-identical sums (absmax 0).

#define LN_BATCH   8192
#define LN_N       4096
#define LN_THREADS 256            // 4 waves; one row per iteration per block
#define LN_WAVES   4
#define LN_GRID    1024           // 4 blocks/CU (LDS-capped), all co-resident
#define LN_ROWS_PB (LN_BATCH / LN_GRID)   // 8 rows per block
#define LN_EPS     1e-6

typedef float vfloat4 __attribute__((ext_vector_type(4)));

__device__ __forceinline__ double wave_allreduce_add(double s) {
#pragma unroll
    for (int off = 1; off < 64; off <<= 1)
        s += __shfl_xor(s, off, 64);
    return s;
}

__global__ __launch_bounds__(LN_THREADS)
void spike_layernorm_kernel(const float* __restrict__ x, float* __restrict__ out) {
    const int wave = threadIdx.x >> 6;
    const int lane = threadIdx.x & 63;

    __shared__ float buf[2][LN_N];            // 2 x 16 KB row double-buffer
    __shared__ double red[2][2][LN_WAVES];    // [row parity][phase][wave]

    // This lane's float offset within a row: wave quarter + DMA slot layout.
    // DMA i covers bytes [wave*4096 + i*1024, +1024): lane L -> +L*16.
    const int fbase = wave * 1024 + lane * 4;

    // Stage row r into buf[b]: 4 async 16B DMAs per lane.
    // LDS dest is WAVE-UNIFORM (no lane term) -- HW adds lane*16.
    // Global src is per-lane. Mapping matches fbase exactly.
    auto stage = [&](int b, int r) {
        const float* g = x + (size_t)r * LN_N + fbase;
#pragma unroll
        for (int i = 0; i < 4; ++i) {
            __builtin_amdgcn_global_load_lds(
                (const __attribute__((address_space(1))) void*)(g + i * 256),
                (__attribute__((address_space(3))) void*)(&buf[b][wave * 1024 + i * 256]),
                16, 0, 0);
        }
    };

    // Prologue: stage row blockIdx.x into buf[0]; pin its queue position.
    stage(0, blockIdx.x);
    asm volatile("" ::: "memory");

#pragma unroll
    for (int it = 0; it < LN_ROWS_PB; ++it) {
        const int r = blockIdx.x + it * LN_GRID;
        const int p = it & 1;

        // Issue next row's DMAs before consuming current row.
        if (it + 1 < LN_ROWS_PB)
            stage(p ^ 1, r + LN_GRID);

        // Wait for THIS row's 4 DMAs (oldest); keep newer ops in flight.
        //   it==0:    outstanding = DMA(0)x4, DMA(1)x4          -> vmcnt(4)
        //   middle:   DMA(it)x4 + {stores(it-1), DMA(it+1)}x8    -> vmcnt(8)
        //   last:     drain everything (end of pipeline)         -> vmcnt(0)
        if (it == 0)
            asm volatile("s_waitcnt vmcnt(4)" ::: "memory");
        else if (it == LN_ROWS_PB - 1)
            asm volatile("s_waitcnt vmcnt(0)" ::: "memory");
        else
            asm volatile("s_waitcnt vmcnt(8)" ::: "memory");

        // Read this wave's quarter back from LDS (same elements as v3).
        vfloat4 v[4];
#pragma unroll
        for (int i = 0; i < 4; ++i)
            v[i] = *reinterpret_cast<const vfloat4*>(&buf[p][fbase + i * 256]);

        // ---- Pass 1: FP64 sum -> mean ----
        double s0 = 0.0, s1 = 0.0;
#pragma unroll
        for (int i = 0; i < 4; ++i) {
            s0 += (double)v[i].x + (double)v[i].y;
            s1 += (double)v[i].z + (double)v[i].w;
        }
        double s = wave_allreduce_add(s0 + s1);
        if (lane == 0) red[p][0][wave] = s;
        asm volatile("s_waitcnt lgkmcnt(0)" ::: "memory");
        __builtin_amdgcn_s_barrier();          // raw: does NOT drain vmcnt
        const double mean =
            ((red[p][0][0] + red[p][0][1]) + (red[p][0][2] + red[p][0][3])) * (1.0 / LN_N);

        // ---- Pass 2: FP64 sum of (x-mean)^2 -> var ----
        double q0 = 0.0, q1 = 0.0;
#pragma unroll
        for (int i = 0; i < 4; ++i) {
            double d;
            d = (double)v[i].x - mean; q0 += d * d;
            d = (double)v[i].y - mean; q1 += d * d;
            d = (double)v[i].z - mean; q0 += d * d;
            d = (double)v[i].w - mean; q1 += d * d;
        }
        double q = wave_allreduce_add(q0 + q1);
        if (lane == 0) red[p][1][wave] = q;
        asm volatile("s_waitcnt lgkmcnt(0)" ::: "memory");
        __builtin_amdgcn_s_barrier();          // raw: does NOT drain vmcnt
        const double var =
            ((red[p][1][0] + red[p][1][1]) + (red[p][1][2] + red[p][1][3])) * (1.0 / LN_N);

        // ---- NR reciprocal refinement (wave-uniform on all lanes) ----
        const double vpe = var + LN_EPS;
        double y = 1.0 / vpe;
#pragma unroll
        for (int nr = 0; nr < 5; ++nr)
            y = 0.5 * y * (3.0 - vpe * (y * y));

        // ---- Pass 3: out = fp32((x64 - mean) * y), NT streaming stores ----
        float* __restrict__ orow = out + (size_t)r * LN_N + fbase;
#pragma unroll
        for (int i = 0; i < 4; ++i) {
            vfloat4 o;
            o.x = (float)(((double)v[i].x - mean) * y);
            o.y = (float)(((double)v[i].y - mean) * y);
            o.z = (float)(((double)v[i].z - mean) * y);
            o.w = (float)(((double)v[i].w - mean) * y);
            __builtin_nontemporal_store(o, reinterpret_cast<vfloat4*>(orow + i * 256));
        }
    }
}

extern "C" void kernel_launch(void* const* d_in, const int* in_sizes, int n_in,
                              void* d_out, int out_size, void* d_ws, size_t ws_size,
                              hipStream_t stream) {
    const float* x = (const float*)d_in[0];
    float* out = (float*)d_out;
    spike_layernorm_kernel<<<LN_GRID, LN_THREADS, 0, stream>>>(x, out);
}